// Round 13
// baseline (444.588 us; speedup 1.0000x reference)
//
#include <hip/hip_runtime.h>
#include <hip/hip_bf16.h>
#include <stdint.h>

typedef unsigned short u16;
typedef __attribute__((ext_vector_type(8))) short short8;
typedef __attribute__((ext_vector_type(4))) float f32x4;

#define T_TOK 2048
#define H_DIM 1024
#define E_NUM 16
#define TWO_I 2048
#define I_DIM 1024
#define ALPHA 1.702f
#define LIMIT 7.0f
// counters padded to 256B (64 ints) apart to avoid same-cache-line atomic serialization
#define CNT_STRIDE 64

__device__ __forceinline__ u16 f2b(float f) {
    uint32_t x = __builtin_bit_cast(uint32_t, f);
    uint32_t r = x + 0x7fffu + ((x >> 16) & 1u);
    return (u16)(r >> 16);
}
__device__ __forceinline__ short8 pack8(float4 a, float4 b) {
    short8 r;
    r[0] = (short)f2b(a.x); r[1] = (short)f2b(a.y);
    r[2] = (short)f2b(a.z); r[3] = (short)f2b(a.w);
    r[4] = (short)f2b(b.x); r[5] = (short)f2b(b.y);
    r[6] = (short)f2b(b.z); r[7] = (short)f2b(b.w);
    return r;
}

// async global->LDS direct load, 16B per lane (dest is wave-linear: base + lane*16)
typedef __attribute__((address_space(1))) void gas_void;
typedef __attribute__((address_space(3))) void las_void;
__device__ __forceinline__ void gl_lds16(const void* g, void* l) {
    __builtin_amdgcn_global_load_lds((gas_void*)g, (las_void*)l, 16, 0, 0);
}

// B-fragment loader for the fp32 fallback path (packs to bf16 at LDS store)
template<typename BT> struct BFrag;
template<> struct BFrag<u16> {
    short8 v;
    __device__ __forceinline__ void load(const u16* p) { v = *(const short8*)p; }
    __device__ __forceinline__ short8 get() const { return v; }
};
template<> struct BFrag<float> {
    float4 a, b;
    __device__ __forceinline__ void load(const float* p) {
        const float4* q = (const float4*)p; a = q[0]; b = q[1];
    }
    __device__ __forceinline__ short8 get() const { return pack8(a, b); }
};

// ---------------------------------------------------------------------------
// Kernel 1: RMSNorm + gate + top-4 + softmax + expert scatter. 1 block/token.
// Also writes out = x (residual init) AND (big path) converts both weight
// tensors fp32->bf16 as a grid-stride tail -- the conversion rides inside
// this dispatch instead of a separate serialized cvt kernel.
// ---------------------------------------------------------------------------
__global__ __launch_bounds__(256) void prep_kernel(
    const float* __restrict__ x, const float* __restrict__ scale,
    const float* __restrict__ gw, const float* __restrict__ gb,
    u16* __restrict__ t_out, int* __restrict__ cnt,
    int* __restrict__ pairs, float* __restrict__ pweight,
    float* __restrict__ out,
    const float* __restrict__ w1f, u16* __restrict__ w1b, int n1,   // float4 counts
    const float* __restrict__ w2f, u16* __restrict__ w2b, int n2)
{
    const int t = blockIdx.x, tid = threadIdx.x;
    const int lane = tid & 63, wid = tid >> 6;
    __shared__ float red[4];
    __shared__ float g4[4][16];
    __shared__ float gsh[16];
    __shared__ float rstd_sh;

    const float4 xv = ((const float4*)(x + (size_t)t * H_DIM))[tid];
    ((float4*)(out + (size_t)t * H_DIM))[tid] = xv;   // residual init
    float ss = xv.x*xv.x + xv.y*xv.y + xv.z*xv.z + xv.w*xv.w;
#pragma unroll
    for (int off = 32; off > 0; off >>= 1) ss += __shfl_down(ss, off);
    if (lane == 0) red[wid] = ss;
    __syncthreads();
    if (tid == 0) rstd_sh = rsqrtf((red[0]+red[1]+red[2]+red[3]) * (1.f/1024.f) + 1e-5f);
    __syncthreads();
    const float rstd = rstd_sh;
    const float4 sc = ((const float4*)scale)[tid];
    float4 tv;
    tv.x = xv.x * rstd * sc.x; tv.y = xv.y * rstd * sc.y;
    tv.z = xv.z * rstd * sc.z; tv.w = xv.w * rstd * sc.w;
    {
        uint32_t lo = (uint32_t)f2b(tv.x) | ((uint32_t)f2b(tv.y) << 16);
        uint32_t hi = (uint32_t)f2b(tv.z) | ((uint32_t)f2b(tv.w) << 16);
        uint2 p; p.x = lo; p.y = hi;
        *(uint2*)(t_out + (size_t)t * H_DIM + tid * 4) = p;
    }
    float part[16];
#pragma unroll
    for (int e = 0; e < 16; e++) {
        const float4 w4 = ((const float4*)(gw + (size_t)e * H_DIM))[tid];
        part[e] = tv.x*w4.x + tv.y*w4.y + tv.z*w4.z + tv.w*w4.w;
    }
#pragma unroll
    for (int e = 0; e < 16; e++) {
        float v = part[e];
#pragma unroll
        for (int off = 32; off > 0; off >>= 1) v += __shfl_down(v, off);
        if (lane == 0) g4[wid][e] = v;
    }
    __syncthreads();
    if (tid < 16) gsh[tid] = g4[0][tid] + g4[1][tid] + g4[2][tid] + g4[3][tid] + gb[tid];
    __syncthreads();
    if (tid == 0) {
        unsigned mask = 0;
        float vals[4]; int idxs[4];
#pragma unroll
        for (int k = 0; k < 4; k++) {
            float best = -1e30f; int bi = 0;
            for (int e = 0; e < 16; e++)
                if (!((mask >> e) & 1u) && gsh[e] > best) { best = gsh[e]; bi = e; }
            mask |= 1u << bi; vals[k] = best; idxs[k] = bi;
        }
        float m = vals[0], s = 0.f, w[4];
#pragma unroll
        for (int k = 0; k < 4; k++) { w[k] = __expf(vals[k] - m); s += w[k]; }
        float inv = 1.f / s;
#pragma unroll
        for (int k = 0; k < 4; k++) {
            int slot = atomicAdd(&cnt[idxs[k] * CNT_STRIDE], 1);
            pairs[idxs[k] * 2048 + slot] = t * 4 + k;
            pweight[t * 4 + k] = w[k] * inv;
        }
    }

    // ---- fused weight conversion tail (big path only; n1=n2=0 otherwise) ----
    if (n1 == 0) return;
    int i = blockIdx.x * 256 + tid;            // pair-of-float4 index
    int stride = gridDim.x * 256;
    int p1 = n1 >> 1, ptot = (n1 + n2) >> 1;
    for (; i < ptot; i += stride) {
        const float* in; u16* o; int j;
        if (i < p1) { in = w1f; o = w1b; j = i; }
        else        { in = w2f; o = w2b; j = i - p1; }
        float4 a = ((const float4*)in)[2 * j];
        float4 b = ((const float4*)in)[2 * j + 1];
        uint4 p;
        p.x = (uint32_t)f2b(a.x) | ((uint32_t)f2b(a.y) << 16);
        p.y = (uint32_t)f2b(a.z) | ((uint32_t)f2b(a.w) << 16);
        p.z = (uint32_t)f2b(b.x) | ((uint32_t)f2b(b.y) << 16);
        p.w = (uint32_t)f2b(b.z) | ((uint32_t)f2b(b.w) << 16);
        ((uint4*)o)[j] = p;
    }
}

// ---------------------------------------------------------------------------
// Kernel 2: GEMM1 (h = t @ W1^T + b1) + SwiGLU -> act (bf16).
// R6/R10-verified structure: 128x128 tile, 4 waves, gl_lds width-16 into
// linear [128][64] LDS, K-chunk XOR swizzle (0 bank conflicts measured),
// 2 barriers per K-step, multi-block/CU co-residency.
// grid: x=nt(16), y=mt(16 early-exit), z=e.
// ---------------------------------------------------------------------------
template<typename BT>
__global__ __launch_bounds__(256, 1) void ffn1_kernel(
    const u16* __restrict__ t_ws, const BT* __restrict__ w1,
    const float* __restrict__ b1, const int* __restrict__ cnt,
    const int* __restrict__ pairs, u16* __restrict__ act)
{
    const int e = blockIdx.z, nt = blockIdx.x, mt = blockIdx.y;
    const int cnt_e = cnt[e * CNT_STRIDE];
    if (mt * 128 >= cnt_e) return;
    const int tid = threadIdx.x;

    __shared__ u16 As[128 * 64];   // linear, no pad (global_load_lds dest)
    __shared__ u16 Bs[128 * 64];

    const BT* w1e = w1 + (size_t)e * TWO_I * H_DIM;
    const int* plist = pairs + e * 2048;

    const u16* aptr[4]; const BT* bptr[4]; int ldsoff[4];
#pragma unroll
    for (int i = 0; i < 4; i++) {
        int c = tid + i * 256;
        int r = c >> 3, kc = c & 7;
        int kcs = kc ^ (r & 7);            // inverse-swizzled source chunk
        int gr = mt * 128 + r;
        int info = (gr < cnt_e) ? plist[gr] : plist[0];
        aptr[i] = t_ws + (size_t)(info >> 2) * H_DIM + kcs * 8;
        ldsoff[i] = c * 8;                 // linear LDS dest (u16 units)
        // column permutation: tile pairs (even h-cols, odd h-cols)
        int t16 = r >> 4, l16 = r & 15;
        int hcol = nt * 128 + (t16 >> 1) * 32 + l16 * 2 + (t16 & 1);
        bptr[i] = w1e + (size_t)hcol * H_DIM + kcs * 8;
    }

    const int lane = tid & 63, wid = tid >> 6;
    const int wm = wid >> 1, wn = wid & 1;
    const int l15 = lane & 15, quad = lane >> 4;
    const int swz = l15 & 7;

    f32x4 acc[4][4];
#pragma unroll
    for (int mi = 0; mi < 4; mi++)
#pragma unroll
        for (int ni = 0; ni < 4; ni++) acc[mi][ni] = (f32x4){0.f, 0.f, 0.f, 0.f};

    for (int ki = 0; ki < 16; ki++) {
        __syncthreads();                   // prior iter's readers done
        if constexpr (sizeof(BT) == 2) {
#pragma unroll
            for (int i = 0; i < 4; i++) gl_lds16(aptr[i] + ki * 64, &As[ldsoff[i]]);
#pragma unroll
            for (int i = 0; i < 4; i++) gl_lds16((const u16*)bptr[i] + ki * 64, &Bs[ldsoff[i]]);
        } else {
            short8 ta[4]; BFrag<BT> fb[4];
#pragma unroll
            for (int i = 0; i < 4; i++) ta[i] = *(const short8*)(aptr[i] + ki * 64);
#pragma unroll
            for (int i = 0; i < 4; i++) fb[i].load(bptr[i] + ki * 64);
#pragma unroll
            for (int i = 0; i < 4; i++) *(short8*)(&As[ldsoff[i]]) = ta[i];
#pragma unroll
            for (int i = 0; i < 4; i++) *(short8*)(&Bs[ldsoff[i]]) = fb[i].get();
        }
        __syncthreads();                   // loads drained (vmcnt0 at barrier)
#pragma unroll
        for (int ks = 0; ks < 2; ks++) {
            short8 af[4], bfr[4];
#pragma unroll
            for (int mi = 0; mi < 4; mi++)
                af[mi] = *(const short8*)(&As[(wm * 64 + mi * 16 + l15) * 64 + (((ks << 2) + quad) ^ swz) * 8]);
#pragma unroll
            for (int ni = 0; ni < 4; ni++)
                bfr[ni] = *(const short8*)(&Bs[(wn * 64 + ni * 16 + l15) * 64 + (((ks << 2) + quad) ^ swz) * 8]);
#pragma unroll
            for (int mi = 0; mi < 4; mi++)
#pragma unroll
                for (int ni = 0; ni < 4; ni++)
                    acc[mi][ni] = __builtin_amdgcn_mfma_f32_16x16x32_bf16(af[mi], bfr[ni], acc[mi][ni], 0, 0, 0);
        }
    }

    // epilogue: SwiGLU in-register (tile 2q=even h-cols, 2q+1=odd h-cols)
#pragma unroll
    for (int mi = 0; mi < 4; mi++) {
        int rloc = wm * 64 + mi * 16 + quad * 4;
        int rinfo[4]; bool rval[4];
#pragma unroll
        for (int rg = 0; rg < 4; rg++) {
            int gr = mt * 128 + rloc + rg;
            rval[rg] = gr < cnt_e;
            rinfo[rg] = rval[rg] ? plist[gr] : 0;
        }
#pragma unroll
        for (int qi = 0; qi < 2; qi++) {
            int actcol = nt * 64 + (wn * 2 + qi) * 16 + l15;
            float be = b1[e * TWO_I + 2 * actcol];
            float bo = b1[e * TWO_I + 2 * actcol + 1];
            f32x4 De = acc[mi][qi * 2], Do = acc[mi][qi * 2 + 1];
#pragma unroll
            for (int rg = 0; rg < 4; rg++) {
                if (!rval[rg]) continue;
                float he = De[rg] + be, ho = Do[rg] + bo;
                float glu = fminf(he, LIMIT);
                float lin = fminf(fmaxf(ho, -LIMIT), LIMIT);
                float a = glu * (1.f / (1.f + __expf(-ALPHA * glu))) * (lin + 1.f);
                act[(size_t)rinfo[rg] * I_DIM + actcol] = f2b(a);
            }
        }
    }
}

// ---------------------------------------------------------------------------
// Kernel 3: GEMM2 (y = act @ W2^T + b2) * softmax_weight -> atomicAdd into out
// (out pre-initialized to x by prep_kernel). R6/R10-verified structure.
// grid: x=nt(8), y=mt(16 early-exit), z=e.
// ---------------------------------------------------------------------------
template<typename BT>
__global__ __launch_bounds__(256, 1) void ffn2_kernel(
    const u16* __restrict__ act, const BT* __restrict__ w2,
    const float* __restrict__ b2, const int* __restrict__ cnt,
    const int* __restrict__ pairs, const float* __restrict__ pweight,
    float* __restrict__ out)
{
    const int e = blockIdx.z, nt = blockIdx.x, mt = blockIdx.y;
    const int cnt_e = cnt[e * CNT_STRIDE];
    if (mt * 128 >= cnt_e) return;
    const int tid = threadIdx.x;

    __shared__ u16 As[128 * 64];
    __shared__ u16 Bs[128 * 64];

    const BT* w2e = w2 + (size_t)e * H_DIM * I_DIM;
    const int* plist = pairs + e * 2048;

    const u16* aptr[4]; const BT* bptr[4]; int ldsoff[4];
#pragma unroll
    for (int i = 0; i < 4; i++) {
        int c = tid + i * 256;
        int r = c >> 3, kc = c & 7;
        int kcs = kc ^ (r & 7);
        int gr = mt * 128 + r;
        int info = (gr < cnt_e) ? plist[gr] : plist[0];
        aptr[i] = act + (size_t)info * I_DIM + kcs * 8;
        ldsoff[i] = c * 8;
        bptr[i] = w2e + (size_t)(nt * 128 + r) * I_DIM + kcs * 8;
    }

    const int lane = tid & 63, wid = tid >> 6;
    const int wm = wid >> 1, wn = wid & 1;
    const int l15 = lane & 15, quad = lane >> 4;
    const int swz = l15 & 7;

    f32x4 acc[4][4];
#pragma unroll
    for (int mi = 0; mi < 4; mi++)
#pragma unroll
        for (int ni = 0; ni < 4; ni++) acc[mi][ni] = (f32x4){0.f, 0.f, 0.f, 0.f};

    for (int ki = 0; ki < 16; ki++) {
        __syncthreads();
        if constexpr (sizeof(BT) == 2) {
#pragma unroll
            for (int i = 0; i < 4; i++) gl_lds16(aptr[i] + ki * 64, &As[ldsoff[i]]);
#pragma unroll
            for (int i = 0; i < 4; i++) gl_lds16((const u16*)bptr[i] + ki * 64, &Bs[ldsoff[i]]);
        } else {
            short8 ta[4]; BFrag<BT> fb[4];
#pragma unroll
            for (int i = 0; i < 4; i++) ta[i] = *(const short8*)(aptr[i] + ki * 64);
#pragma unroll
            for (int i = 0; i < 4; i++) fb[i].load(bptr[i] + ki * 64);
#pragma unroll
            for (int i = 0; i < 4; i++) *(short8*)(&As[ldsoff[i]]) = ta[i];
#pragma unroll
            for (int i = 0; i < 4; i++) *(short8*)(&Bs[ldsoff[i]]) = fb[i].get();
        }
        __syncthreads();
#pragma unroll
        for (int ks = 0; ks < 2; ks++) {
            short8 af[4], bfr[4];
#pragma unroll
            for (int mi = 0; mi < 4; mi++)
                af[mi] = *(const short8*)(&As[(wm * 64 + mi * 16 + l15) * 64 + (((ks << 2) + quad) ^ swz) * 8]);
#pragma unroll
            for (int ni = 0; ni < 4; ni++)
                bfr[ni] = *(const short8*)(&Bs[(wn * 64 + ni * 16 + l15) * 64 + (((ks << 2) + quad) ^ swz) * 8]);
#pragma unroll
            for (int mi = 0; mi < 4; mi++)
#pragma unroll
                for (int ni = 0; ni < 4; ni++)
                    acc[mi][ni] = __builtin_amdgcn_mfma_f32_16x16x32_bf16(af[mi], bfr[ni], acc[mi][ni], 0, 0, 0);
        }
    }

#pragma unroll
    for (int mi = 0; mi < 4; mi++) {
        int rloc = wm * 64 + mi * 16 + quad * 4;
        int rinfo[4]; bool rval[4]; float wp[4];
#pragma unroll
        for (int rg = 0; rg < 4; rg++) {
            int gr = mt * 128 + rloc + rg;
            rval[rg] = gr < cnt_e;
            rinfo[rg] = rval[rg] ? plist[gr] : 0;
            wp[rg] = rval[rg] ? pweight[rinfo[rg]] : 0.f;
        }
#pragma unroll
        for (int ni = 0; ni < 4; ni++) {
            int hc = nt * 128 + wn * 64 + ni * 16 + l15;
            float bv = b2[e * H_DIM + hc];
#pragma unroll
            for (int rg = 0; rg < 4; rg++) {
                if (!rval[rg]) continue;
                float val = (acc[mi][ni][rg] + bv) * wp[rg];
                atomicAdd(&out[(size_t)(rinfo[rg] >> 2) * H_DIM + hc], val);
            }
        }
    }
}

extern "C" void kernel_launch(void* const* d_in, const int* in_sizes, int n_in,
                              void* d_out, int out_size, void* d_ws, size_t ws_size,
                              hipStream_t stream)
{
    const float* x      = (const float*)d_in[0];
    const float* nscale = (const float*)d_in[1];
    const float* gate_w = (const float*)d_in[2];
    const float* gate_b = (const float*)d_in[3];
    const float* mlp1_w = (const float*)d_in[4];
    const float* mlp1_b = (const float*)d_in[5];
    const float* mlp2_w = (const float*)d_in[6];
    const float* mlp2_b = (const float*)d_in[7];
    float* out = (float*)d_out;

    char* ws = (char*)d_ws;
    u16*   t_ws  = (u16*)(ws);                          //  0M: 4 MiB bf16 tokens
    u16*   act   = (u16*)(ws + (4ull << 20));           //  4M: 16 MiB bf16 act
    int*   cnt   = (int*)(ws + (28ull << 20));          // 28M: padded counters (16 x 256B)
    int*   pairs = (int*)(ws + (28ull << 20) + 4096);
    float* pw    = (float*)(ws + (28ull << 20) + 4096 + E_NUM * 2048 * 4);
    u16*   w1b   = (u16*)(ws + (32ull << 20));          // 32M: 64 MiB bf16 W1
    u16*   w2b   = (u16*)(ws + (96ull << 20));          // 96M: 32 MiB bf16 W2

    const bool big = ws_size >= (128ull << 20);

    hipMemsetAsync(cnt, 0, E_NUM * CNT_STRIDE * sizeof(int), stream);

    if (big) {
        // conversion fused into prep (grid-stride tail)
        prep_kernel<<<T_TOK, 256, 0, stream>>>(x, nscale, gate_w, gate_b, t_ws, cnt, pairs, pw, out,
                                               mlp1_w, w1b, E_NUM * TWO_I * H_DIM / 4,
                                               mlp2_w, w2b, E_NUM * H_DIM * I_DIM / 4);
        ffn1_kernel<u16><<<dim3(16, 16, E_NUM), 256, 0, stream>>>(t_ws, w1b, mlp1_b, cnt, pairs, act);
        ffn2_kernel<u16><<<dim3(8, 16, E_NUM), 256, 0, stream>>>(act, w2b, mlp2_b, cnt, pairs, pw, out);
    } else {
        prep_kernel<<<T_TOK, 256, 0, stream>>>(x, nscale, gate_w, gate_b, t_ws, cnt, pairs, pw, out,
                                               nullptr, nullptr, 0, nullptr, nullptr, 0);
        ffn1_kernel<float><<<dim3(16, 16, E_NUM), 256, 0, stream>>>(t_ws, mlp1_w, mlp1_b, cnt, pairs, act);
        ffn2_kernel<float><<<dim3(8, 16, E_NUM), 256, 0, stream>>>(act, mlp2_w, mlp2_b, cnt, pairs, pw, out);
    }
}

// Round 14
// 402.852 us; speedup vs baseline: 1.1036x; 1.1036x over previous
//
#include <hip/hip_runtime.h>
#include <hip/hip_bf16.h>
#include <stdint.h>

typedef unsigned short u16;
typedef __attribute__((ext_vector_type(8))) short short8;
typedef __attribute__((ext_vector_type(4))) float f32x4;

#define T_TOK 2048
#define H_DIM 1024
#define E_NUM 16
#define TWO_I 2048
#define I_DIM 1024
#define ALPHA 1.702f
#define LIMIT 7.0f
// counters padded to 256B (64 ints) apart to avoid same-cache-line atomic serialization
#define CNT_STRIDE 64

__device__ __forceinline__ u16 f2b(float f) {
    uint32_t x = __builtin_bit_cast(uint32_t, f);
    uint32_t r = x + 0x7fffu + ((x >> 16) & 1u);
    return (u16)(r >> 16);
}
__device__ __forceinline__ short8 pack8(float4 a, float4 b) {
    short8 r;
    r[0] = (short)f2b(a.x); r[1] = (short)f2b(a.y);
    r[2] = (short)f2b(a.z); r[3] = (short)f2b(a.w);
    r[4] = (short)f2b(b.x); r[5] = (short)f2b(b.y);
    r[6] = (short)f2b(b.z); r[7] = (short)f2b(b.w);
    return r;
}

// async global->LDS direct load, 16B per lane (dest is wave-linear: base + lane*16)
typedef __attribute__((address_space(1))) void gas_void;
typedef __attribute__((address_space(3))) void las_void;
__device__ __forceinline__ void gl_lds16(const void* g, void* l) {
    __builtin_amdgcn_global_load_lds((gas_void*)g, (las_void*)l, 16, 0, 0);
}

// fp32 B-fragment: 32B global load, packs to bf16 at LDS store
struct BFragF {
    float4 a, b;
    __device__ __forceinline__ void load(const float* p) {
        const float4* q = (const float4*)p; a = q[0]; b = q[1];
    }
    __device__ __forceinline__ short8 get() const { return pack8(a, b); }
};

// ---------------------------------------------------------------------------
// Kernel 1: RMSNorm + gate + top-4 + softmax + expert scatter. 1 block/token.
// Also writes out = x (residual init; ffn2 accumulates on top).
// ---------------------------------------------------------------------------
__global__ __launch_bounds__(256) void prep_kernel(
    const float* __restrict__ x, const float* __restrict__ scale,
    const float* __restrict__ gw, const float* __restrict__ gb,
    u16* __restrict__ t_out, int* __restrict__ cnt,
    int* __restrict__ pairs, float* __restrict__ pweight,
    float* __restrict__ out)
{
    const int t = blockIdx.x, tid = threadIdx.x;
    const int lane = tid & 63, wid = tid >> 6;
    __shared__ float red[4];
    __shared__ float g4[4][16];
    __shared__ float gsh[16];
    __shared__ float rstd_sh;

    const float4 xv = ((const float4*)(x + (size_t)t * H_DIM))[tid];
    ((float4*)(out + (size_t)t * H_DIM))[tid] = xv;   // residual init
    float ss = xv.x*xv.x + xv.y*xv.y + xv.z*xv.z + xv.w*xv.w;
#pragma unroll
    for (int off = 32; off > 0; off >>= 1) ss += __shfl_down(ss, off);
    if (lane == 0) red[wid] = ss;
    __syncthreads();
    if (tid == 0) rstd_sh = rsqrtf((red[0]+red[1]+red[2]+red[3]) * (1.f/1024.f) + 1e-5f);
    __syncthreads();
    const float rstd = rstd_sh;
    const float4 sc = ((const float4*)scale)[tid];
    float4 tv;
    tv.x = xv.x * rstd * sc.x; tv.y = xv.y * rstd * sc.y;
    tv.z = xv.z * rstd * sc.z; tv.w = xv.w * rstd * sc.w;
    {
        uint32_t lo = (uint32_t)f2b(tv.x) | ((uint32_t)f2b(tv.y) << 16);
        uint32_t hi = (uint32_t)f2b(tv.z) | ((uint32_t)f2b(tv.w) << 16);
        uint2 p; p.x = lo; p.y = hi;
        *(uint2*)(t_out + (size_t)t * H_DIM + tid * 4) = p;
    }
    float part[16];
#pragma unroll
    for (int e = 0; e < 16; e++) {
        const float4 w4 = ((const float4*)(gw + (size_t)e * H_DIM))[tid];
        part[e] = tv.x*w4.x + tv.y*w4.y + tv.z*w4.z + tv.w*w4.w;
    }
#pragma unroll
    for (int e = 0; e < 16; e++) {
        float v = part[e];
#pragma unroll
        for (int off = 32; off > 0; off >>= 1) v += __shfl_down(v, off);
        if (lane == 0) g4[wid][e] = v;
    }
    __syncthreads();
    if (tid < 16) gsh[tid] = g4[0][tid] + g4[1][tid] + g4[2][tid] + g4[3][tid] + gb[tid];
    __syncthreads();
    if (tid == 0) {
        unsigned mask = 0;
        float vals[4]; int idxs[4];
#pragma unroll
        for (int k = 0; k < 4; k++) {
            float best = -1e30f; int bi = 0;
            for (int e = 0; e < 16; e++)
                if (!((mask >> e) & 1u) && gsh[e] > best) { best = gsh[e]; bi = e; }
            mask |= 1u << bi; vals[k] = best; idxs[k] = bi;
        }
        float m = vals[0], s = 0.f, w[4];
#pragma unroll
        for (int k = 0; k < 4; k++) { w[k] = __expf(vals[k] - m); s += w[k]; }
        float inv = 1.f / s;
#pragma unroll
        for (int k = 0; k < 4; k++) {
            int slot = atomicAdd(&cnt[idxs[k] * CNT_STRIDE], 1);
            pairs[idxs[k] * 2048 + slot] = t * 4 + k;
            pweight[t * 4 + k] = w[k] * inv;
        }
    }
}

// ---------------------------------------------------------------------------
// Kernel 2: GEMM1 (h = t @ W1^T + b1) + SwiGLU -> act (bf16).
// 64x128 tile (M halved vs R12 to double live blocks: ~8/CU supplied,
// 24 KB LDS + ~90 VGPR -> 5-6 blocks/CU resident for latency hiding).
// W1 read as fp32, packed to bf16 at B-staging ds_write (no cvt pass).
// A: gl_lds w16, pre-swizzled source, linear LDS. B: reg prefetch under MFMA.
// grid: x=nt(16), y=mt(32 early-exit), z=e.
// ---------------------------------------------------------------------------
__global__ __launch_bounds__(256, 1) void ffn1_kernel(
    const u16* __restrict__ t_ws, const float* __restrict__ w1,
    const float* __restrict__ b1, const int* __restrict__ cnt,
    const int* __restrict__ pairs, u16* __restrict__ act)
{
    const int e = blockIdx.z, nt = blockIdx.x, mt = blockIdx.y;
    const int cnt_e = cnt[e * CNT_STRIDE];
    if (mt * 64 >= cnt_e) return;
    const int tid = threadIdx.x;

    __shared__ u16 As[64 * 64];    // 8 KB, linear (gl_lds dest)
    __shared__ u16 Bs[128 * 64];   // 16 KB, swizzled ds_write

    const float* w1e = w1 + (size_t)e * TWO_I * H_DIM;
    const int* plist = pairs + e * 2048;

    // A staging: 64 rows x 8 chunks = 512 -> 2 per thread
    const u16* aptr[2]; int ldsA[2];
#pragma unroll
    for (int i = 0; i < 2; i++) {
        int c = tid + i * 256;
        int r = c >> 3, kc = c & 7;
        int kcs = kc ^ (r & 7);
        int gr = mt * 64 + r;
        int info = (gr < cnt_e) ? plist[gr] : plist[0];
        aptr[i] = t_ws + (size_t)(info >> 2) * H_DIM + kcs * 8;  // pre-swizzled source
        ldsA[i] = c * 8;
    }
    // B staging: 128 rows x 8 chunks = 1024 -> 4 per thread
    const float* bptr[4]; int ldsB[4];
#pragma unroll
    for (int i = 0; i < 4; i++) {
        int c = tid + i * 256;
        int r = c >> 3, kc = c & 7;
        int kcs = kc ^ (r & 7);
        // column permutation: 16-row tile pairs = (even h-cols, odd h-cols)
        int t16 = r >> 4, l16 = r & 15;
        int hcol = nt * 128 + (t16 >> 1) * 32 + l16 * 2 + (t16 & 1);
        bptr[i] = w1e + (size_t)hcol * H_DIM + kc * 8;           // natural source
        ldsB[i] = r * 64 + kcs * 8;        // swizzled LDS dest
    }

    const int lane = tid & 63, wid = tid >> 6;
    const int wm = wid >> 1, wn = wid & 1;     // wave tile: 32 M x 64 N
    const int l15 = lane & 15, quad = lane >> 4;
    const int swz = l15 & 7;

    f32x4 acc[2][4];
#pragma unroll
    for (int mi = 0; mi < 2; mi++)
#pragma unroll
        for (int ni = 0; ni < 4; ni++) acc[mi][ni] = (f32x4){0.f, 0.f, 0.f, 0.f};

    BFragF fb[4];
#pragma unroll
    for (int i = 0; i < 4; i++) fb[i].load(bptr[i]);   // B(0)

    for (int ki = 0; ki < 16; ki++) {
        __syncthreads();                   // prior iter's LDS readers done
#pragma unroll
        for (int i = 0; i < 2; i++) gl_lds16(aptr[i] + ki * 64, &As[ldsA[i]]);
#pragma unroll
        for (int i = 0; i < 4; i++) *(short8*)(&Bs[ldsB[i]]) = fb[i].get();
        __syncthreads();                   // drains vmcnt(A) + lgkm(B)
        if (ki < 15) {                     // prefetch B(ki+1) under MFMA
#pragma unroll
            for (int i = 0; i < 4; i++) fb[i].load(bptr[i] + (ki + 1) * 64);
        }
#pragma unroll
        for (int ks = 0; ks < 2; ks++) {
            short8 af[2], bfr[4];
#pragma unroll
            for (int mi = 0; mi < 2; mi++)
                af[mi] = *(const short8*)(&As[(wm * 32 + mi * 16 + l15) * 64 + (((ks << 2) + quad) ^ swz) * 8]);
#pragma unroll
            for (int ni = 0; ni < 4; ni++)
                bfr[ni] = *(const short8*)(&Bs[(wn * 64 + ni * 16 + l15) * 64 + (((ks << 2) + quad) ^ swz) * 8]);
#pragma unroll
            for (int mi = 0; mi < 2; mi++)
#pragma unroll
                for (int ni = 0; ni < 4; ni++)
                    acc[mi][ni] = __builtin_amdgcn_mfma_f32_16x16x32_bf16(af[mi], bfr[ni], acc[mi][ni], 0, 0, 0);
        }
    }

    // epilogue: SwiGLU in-register (B-row pair 2q/2q+1 = even/odd h-cols)
#pragma unroll
    for (int mi = 0; mi < 2; mi++) {
        int rloc = wm * 32 + mi * 16 + quad * 4;
        int rinfo[4]; bool rval[4];
#pragma unroll
        for (int rg = 0; rg < 4; rg++) {
            int gr = mt * 64 + rloc + rg;
            rval[rg] = gr < cnt_e;
            rinfo[rg] = rval[rg] ? plist[gr] : 0;
        }
#pragma unroll
        for (int qi = 0; qi < 2; qi++) {
            int actcol = nt * 64 + (wn * 2 + qi) * 16 + l15;
            float be = b1[e * TWO_I + 2 * actcol];
            float bo = b1[e * TWO_I + 2 * actcol + 1];
            f32x4 De = acc[mi][qi * 2], Do = acc[mi][qi * 2 + 1];
#pragma unroll
            for (int rg = 0; rg < 4; rg++) {
                if (!rval[rg]) continue;
                float he = De[rg] + be, ho = Do[rg] + bo;
                float glu = fminf(he, LIMIT);
                float lin = fminf(fmaxf(ho, -LIMIT), LIMIT);
                float a = glu * (1.f / (1.f + __expf(-ALPHA * glu))) * (lin + 1.f);
                act[(size_t)rinfo[rg] * I_DIM + actcol] = f2b(a);
            }
        }
    }
}

// ---------------------------------------------------------------------------
// Kernel 3: GEMM2 (y = act @ W2^T + b2) * softmax_weight -> atomicAdd into out
// (out pre-initialized to x by prep_kernel). W2 read as fp32, same staging.
// 64x128 tile. grid: x=nt(8), y=mt(32 early-exit), z=e.
// ---------------------------------------------------------------------------
__global__ __launch_bounds__(256, 1) void ffn2_kernel(
    const u16* __restrict__ act, const float* __restrict__ w2,
    const float* __restrict__ b2, const int* __restrict__ cnt,
    const int* __restrict__ pairs, const float* __restrict__ pweight,
    float* __restrict__ out)
{
    const int e = blockIdx.z, nt = blockIdx.x, mt = blockIdx.y;
    const int cnt_e = cnt[e * CNT_STRIDE];
    if (mt * 64 >= cnt_e) return;
    const int tid = threadIdx.x;

    __shared__ u16 As[64 * 64];
    __shared__ u16 Bs[128 * 64];

    const float* w2e = w2 + (size_t)e * H_DIM * I_DIM;
    const int* plist = pairs + e * 2048;

    const u16* aptr[2]; int ldsA[2];
#pragma unroll
    for (int i = 0; i < 2; i++) {
        int c = tid + i * 256;
        int r = c >> 3, kc = c & 7;
        int kcs = kc ^ (r & 7);
        int gr = mt * 64 + r;
        int info = (gr < cnt_e) ? plist[gr] : plist[0];
        aptr[i] = act + (size_t)info * I_DIM + kcs * 8;
        ldsA[i] = c * 8;
    }
    const float* bptr[4]; int ldsB[4];
#pragma unroll
    for (int i = 0; i < 4; i++) {
        int c = tid + i * 256;
        int r = c >> 3, kc = c & 7;
        int kcs = kc ^ (r & 7);
        bptr[i] = w2e + (size_t)(nt * 128 + r) * I_DIM + kc * 8;
        ldsB[i] = r * 64 + kcs * 8;
    }

    const int lane = tid & 63, wid = tid >> 6;
    const int wm = wid >> 1, wn = wid & 1;
    const int l15 = lane & 15, quad = lane >> 4;
    const int swz = l15 & 7;

    f32x4 acc[2][4];
#pragma unroll
    for (int mi = 0; mi < 2; mi++)
#pragma unroll
        for (int ni = 0; ni < 4; ni++) acc[mi][ni] = (f32x4){0.f, 0.f, 0.f, 0.f};

    BFragF fb[4];
#pragma unroll
    for (int i = 0; i < 4; i++) fb[i].load(bptr[i]);

    for (int ki = 0; ki < 16; ki++) {
        __syncthreads();
#pragma unroll
        for (int i = 0; i < 2; i++) gl_lds16(aptr[i] + ki * 64, &As[ldsA[i]]);
#pragma unroll
        for (int i = 0; i < 4; i++) *(short8*)(&Bs[ldsB[i]]) = fb[i].get();
        __syncthreads();
        if (ki < 15) {
#pragma unroll
            for (int i = 0; i < 4; i++) fb[i].load(bptr[i] + (ki + 1) * 64);
        }
#pragma unroll
        for (int ks = 0; ks < 2; ks++) {
            short8 af[2], bfr[4];
#pragma unroll
            for (int mi = 0; mi < 2; mi++)
                af[mi] = *(const short8*)(&As[(wm * 32 + mi * 16 + l15) * 64 + (((ks << 2) + quad) ^ swz) * 8]);
#pragma unroll
            for (int ni = 0; ni < 4; ni++)
                bfr[ni] = *(const short8*)(&Bs[(wn * 64 + ni * 16 + l15) * 64 + (((ks << 2) + quad) ^ swz) * 8]);
#pragma unroll
            for (int mi = 0; mi < 2; mi++)
#pragma unroll
                for (int ni = 0; ni < 4; ni++)
                    acc[mi][ni] = __builtin_amdgcn_mfma_f32_16x16x32_bf16(af[mi], bfr[ni], acc[mi][ni], 0, 0, 0);
        }
    }

#pragma unroll
    for (int mi = 0; mi < 2; mi++) {
        int rloc = wm * 32 + mi * 16 + quad * 4;
        int rinfo[4]; bool rval[4]; float wp[4];
#pragma unroll
        for (int rg = 0; rg < 4; rg++) {
            int gr = mt * 64 + rloc + rg;
            rval[rg] = gr < cnt_e;
            rinfo[rg] = rval[rg] ? plist[gr] : 0;
            wp[rg] = rval[rg] ? pweight[rinfo[rg]] : 0.f;
        }
#pragma unroll
        for (int ni = 0; ni < 4; ni++) {
            int hc = nt * 128 + wn * 64 + ni * 16 + l15;
            float bv = b2[e * H_DIM + hc];
#pragma unroll
            for (int rg = 0; rg < 4; rg++) {
                if (!rval[rg]) continue;
                float val = (acc[mi][ni][rg] + bv) * wp[rg];
                atomicAdd(&out[(size_t)(rinfo[rg] >> 2) * H_DIM + hc], val);
            }
        }
    }
}

extern "C" void kernel_launch(void* const* d_in, const int* in_sizes, int n_in,
                              void* d_out, int out_size, void* d_ws, size_t ws_size,
                              hipStream_t stream)
{
    const float* x      = (const float*)d_in[0];
    const float* nscale = (const float*)d_in[1];
    const float* gate_w = (const float*)d_in[2];
    const float* gate_b = (const float*)d_in[3];
    const float* mlp1_w = (const float*)d_in[4];
    const float* mlp1_b = (const float*)d_in[5];
    const float* mlp2_w = (const float*)d_in[6];
    const float* mlp2_b = (const float*)d_in[7];
    float* out = (float*)d_out;

    char* ws = (char*)d_ws;
    u16*   t_ws  = (u16*)(ws);                          //  0M: 4 MiB bf16 tokens
    u16*   act   = (u16*)(ws + (4ull << 20));           //  4M: 16 MiB bf16 act
    int*   cnt   = (int*)(ws + (20ull << 20));          // 20M: padded counters (16 x 256B)
    int*   pairs = (int*)(ws + (20ull << 20) + 4096);
    float* pw    = (float*)(ws + (20ull << 20) + 4096 + E_NUM * 2048 * 4);

    hipMemsetAsync(cnt, 0, E_NUM * CNT_STRIDE * sizeof(int), stream);

    prep_kernel<<<T_TOK, 256, 0, stream>>>(x, nscale, gate_w, gate_b, t_ws, cnt, pairs, pw, out);
    ffn1_kernel<<<dim3(16, 32, E_NUM), 256, 0, stream>>>(t_ws, mlp1_w, mlp1_b, cnt, pairs, act);
    ffn2_kernel<<<dim3(8, 32, E_NUM), 256, 0, stream>>>(act, mlp2_w, mlp2_b, cnt, pairs, pw, out);
}

// Round 15
// 400.997 us; speedup vs baseline: 1.1087x; 1.0046x over previous
//
#include <hip/hip_runtime.h>
#include <hip/hip_bf16.h>
#include <stdint.h>

typedef unsigned short u16;
typedef __attribute__((ext_vector_type(8))) short short8;
typedef __attribute__((ext_vector_type(4))) float f32x4;

#define T_TOK 2048
#define H_DIM 1024
#define E_NUM 16
#define TWO_I 2048
#define I_DIM 1024
#define ALPHA 1.702f
#define LIMIT 7.0f
// counters padded to 256B (64 ints) apart to avoid same-cache-line atomic serialization
#define CNT_STRIDE 64

__device__ __forceinline__ u16 f2b(float f) {
    uint32_t x = __builtin_bit_cast(uint32_t, f);
    uint32_t r = x + 0x7fffu + ((x >> 16) & 1u);
    return (u16)(r >> 16);
}

// fp32 B-fragment: 32B global load; packs to bf16 via v_cvt_pk_bf16_f32
// (1 instr per 2 floats, RNE — replaces ~32 bit-twiddle VALU ops per fragment)
struct BFragF {
    float4 a, b;
    __device__ __forceinline__ void load(const float* p) {
        const float4* q = (const float4*)p; a = q[0]; b = q[1];
    }
    __device__ __forceinline__ short8 get() const {
        union { uint32_t u[4]; short8 s; } r;
        asm("v_cvt_pk_bf16_f32 %0, %1, %2" : "=v"(r.u[0]) : "v"(a.x), "v"(a.y));
        asm("v_cvt_pk_bf16_f32 %0, %1, %2" : "=v"(r.u[1]) : "v"(a.z), "v"(a.w));
        asm("v_cvt_pk_bf16_f32 %0, %1, %2" : "=v"(r.u[2]) : "v"(b.x), "v"(b.y));
        asm("v_cvt_pk_bf16_f32 %0, %1, %2" : "=v"(r.u[3]) : "v"(b.z), "v"(b.w));
        return r.s;
    }
};

// async global->LDS direct load, 16B per lane (dest is wave-linear: base + lane*16)
typedef __attribute__((address_space(1))) void gas_void;
typedef __attribute__((address_space(3))) void las_void;
__device__ __forceinline__ void gl_lds16(const void* g, void* l) {
    __builtin_amdgcn_global_load_lds((gas_void*)g, (las_void*)l, 16, 0, 0);
}

// ---------------------------------------------------------------------------
// Kernel 1: RMSNorm + gate + top-4 + softmax + expert scatter. 1 block/token.
// Also writes out = x (residual init; ffn2 accumulates on top).
// ---------------------------------------------------------------------------
__global__ __launch_bounds__(256) void prep_kernel(
    const float* __restrict__ x, const float* __restrict__ scale,
    const float* __restrict__ gw, const float* __restrict__ gb,
    u16* __restrict__ t_out, int* __restrict__ cnt,
    int* __restrict__ pairs, float* __restrict__ pweight,
    float* __restrict__ out)
{
    const int t = blockIdx.x, tid = threadIdx.x;
    const int lane = tid & 63, wid = tid >> 6;
    __shared__ float red[4];
    __shared__ float g4[4][16];
    __shared__ float gsh[16];
    __shared__ float rstd_sh;

    const float4 xv = ((const float4*)(x + (size_t)t * H_DIM))[tid];
    ((float4*)(out + (size_t)t * H_DIM))[tid] = xv;   // residual init
    float ss = xv.x*xv.x + xv.y*xv.y + xv.z*xv.z + xv.w*xv.w;
#pragma unroll
    for (int off = 32; off > 0; off >>= 1) ss += __shfl_down(ss, off);
    if (lane == 0) red[wid] = ss;
    __syncthreads();
    if (tid == 0) rstd_sh = rsqrtf((red[0]+red[1]+red[2]+red[3]) * (1.f/1024.f) + 1e-5f);
    __syncthreads();
    const float rstd = rstd_sh;
    const float4 sc = ((const float4*)scale)[tid];
    float4 tv;
    tv.x = xv.x * rstd * sc.x; tv.y = xv.y * rstd * sc.y;
    tv.z = xv.z * rstd * sc.z; tv.w = xv.w * rstd * sc.w;
    {
        uint32_t lo = (uint32_t)f2b(tv.x) | ((uint32_t)f2b(tv.y) << 16);
        uint32_t hi = (uint32_t)f2b(tv.z) | ((uint32_t)f2b(tv.w) << 16);
        uint2 p; p.x = lo; p.y = hi;
        *(uint2*)(t_out + (size_t)t * H_DIM + tid * 4) = p;
    }
    float part[16];
#pragma unroll
    for (int e = 0; e < 16; e++) {
        const float4 w4 = ((const float4*)(gw + (size_t)e * H_DIM))[tid];
        part[e] = tv.x*w4.x + tv.y*w4.y + tv.z*w4.z + tv.w*w4.w;
    }
#pragma unroll
    for (int e = 0; e < 16; e++) {
        float v = part[e];
#pragma unroll
        for (int off = 32; off > 0; off >>= 1) v += __shfl_down(v, off);
        if (lane == 0) g4[wid][e] = v;
    }
    __syncthreads();
    if (tid < 16) gsh[tid] = g4[0][tid] + g4[1][tid] + g4[2][tid] + g4[3][tid] + gb[tid];
    __syncthreads();
    if (tid == 0) {
        unsigned mask = 0;
        float vals[4]; int idxs[4];
#pragma unroll
        for (int k = 0; k < 4; k++) {
            float best = -1e30f; int bi = 0;
            for (int e = 0; e < 16; e++)
                if (!((mask >> e) & 1u) && gsh[e] > best) { best = gsh[e]; bi = e; }
            mask |= 1u << bi; vals[k] = best; idxs[k] = bi;
        }
        float m = vals[0], s = 0.f, w[4];
#pragma unroll
        for (int k = 0; k < 4; k++) { w[k] = __expf(vals[k] - m); s += w[k]; }
        float inv = 1.f / s;
#pragma unroll
        for (int k = 0; k < 4; k++) {
            int slot = atomicAdd(&cnt[idxs[k] * CNT_STRIDE], 1);
            pairs[idxs[k] * 2048 + slot] = t * 4 + k;
            pweight[t * 4 + k] = w[k] * inv;
        }
    }
}

// ---------------------------------------------------------------------------
// Kernel 2: GEMM1 (h = t @ W1^T + b1) + SwiGLU -> act (bf16).
// 64x128 tile (R14-verified: occupancy 35%, 122 us). W1 read as fp32,
// packed to bf16 at B-staging ds_write via v_cvt_pk_bf16_f32 (this round).
// A: gl_lds w16, pre-swizzled source, linear LDS. B: reg prefetch under MFMA.
// grid: x=nt(16), y=mt(32 early-exit), z=e.
// ---------------------------------------------------------------------------
__global__ __launch_bounds__(256, 1) void ffn1_kernel(
    const u16* __restrict__ t_ws, const float* __restrict__ w1,
    const float* __restrict__ b1, const int* __restrict__ cnt,
    const int* __restrict__ pairs, u16* __restrict__ act)
{
    const int e = blockIdx.z, nt = blockIdx.x, mt = blockIdx.y;
    const int cnt_e = cnt[e * CNT_STRIDE];
    if (mt * 64 >= cnt_e) return;
    const int tid = threadIdx.x;

    __shared__ u16 As[64 * 64];    // 8 KB, linear (gl_lds dest)
    __shared__ u16 Bs[128 * 64];   // 16 KB, swizzled ds_write

    const float* w1e = w1 + (size_t)e * TWO_I * H_DIM;
    const int* plist = pairs + e * 2048;

    // A staging: 64 rows x 8 chunks = 512 -> 2 per thread
    const u16* aptr[2]; int ldsA[2];
#pragma unroll
    for (int i = 0; i < 2; i++) {
        int c = tid + i * 256;
        int r = c >> 3, kc = c & 7;
        int kcs = kc ^ (r & 7);
        int gr = mt * 64 + r;
        int info = (gr < cnt_e) ? plist[gr] : plist[0];
        aptr[i] = t_ws + (size_t)(info >> 2) * H_DIM + kcs * 8;  // pre-swizzled source
        ldsA[i] = c * 8;
    }
    // B staging: 128 rows x 8 chunks = 1024 -> 4 per thread
    const float* bptr[4]; int ldsB[4];
#pragma unroll
    for (int i = 0; i < 4; i++) {
        int c = tid + i * 256;
        int r = c >> 3, kc = c & 7;
        int kcs = kc ^ (r & 7);
        // column permutation: 16-row tile pairs = (even h-cols, odd h-cols)
        int t16 = r >> 4, l16 = r & 15;
        int hcol = nt * 128 + (t16 >> 1) * 32 + l16 * 2 + (t16 & 1);
        bptr[i] = w1e + (size_t)hcol * H_DIM + kc * 8;           // natural source
        ldsB[i] = r * 64 + kcs * 8;        // swizzled LDS dest
    }

    const int lane = tid & 63, wid = tid >> 6;
    const int wm = wid >> 1, wn = wid & 1;     // wave tile: 32 M x 64 N
    const int l15 = lane & 15, quad = lane >> 4;
    const int swz = l15 & 7;

    f32x4 acc[2][4];
#pragma unroll
    for (int mi = 0; mi < 2; mi++)
#pragma unroll
        for (int ni = 0; ni < 4; ni++) acc[mi][ni] = (f32x4){0.f, 0.f, 0.f, 0.f};

    BFragF fb[4];
#pragma unroll
    for (int i = 0; i < 4; i++) fb[i].load(bptr[i]);   // B(0)

    for (int ki = 0; ki < 16; ki++) {
        __syncthreads();                   // prior iter's LDS readers done
#pragma unroll
        for (int i = 0; i < 2; i++) gl_lds16(aptr[i] + ki * 64, &As[ldsA[i]]);
#pragma unroll
        for (int i = 0; i < 4; i++) *(short8*)(&Bs[ldsB[i]]) = fb[i].get();
        __syncthreads();                   // drains vmcnt(A) + lgkm(B)
        if (ki < 15) {                     // prefetch B(ki+1) under MFMA
#pragma unroll
            for (int i = 0; i < 4; i++) fb[i].load(bptr[i] + (ki + 1) * 64);
        }
#pragma unroll
        for (int ks = 0; ks < 2; ks++) {
            short8 af[2], bfr[4];
#pragma unroll
            for (int mi = 0; mi < 2; mi++)
                af[mi] = *(const short8*)(&As[(wm * 32 + mi * 16 + l15) * 64 + (((ks << 2) + quad) ^ swz) * 8]);
#pragma unroll
            for (int ni = 0; ni < 4; ni++)
                bfr[ni] = *(const short8*)(&Bs[(wn * 64 + ni * 16 + l15) * 64 + (((ks << 2) + quad) ^ swz) * 8]);
#pragma unroll
            for (int mi = 0; mi < 2; mi++)
#pragma unroll
                for (int ni = 0; ni < 4; ni++)
                    acc[mi][ni] = __builtin_amdgcn_mfma_f32_16x16x32_bf16(af[mi], bfr[ni], acc[mi][ni], 0, 0, 0);
        }
    }

    // epilogue: SwiGLU in-register (B-row pair 2q/2q+1 = even/odd h-cols)
#pragma unroll
    for (int mi = 0; mi < 2; mi++) {
        int rloc = wm * 32 + mi * 16 + quad * 4;
        int rinfo[4]; bool rval[4];
#pragma unroll
        for (int rg = 0; rg < 4; rg++) {
            int gr = mt * 64 + rloc + rg;
            rval[rg] = gr < cnt_e;
            rinfo[rg] = rval[rg] ? plist[gr] : 0;
        }
#pragma unroll
        for (int qi = 0; qi < 2; qi++) {
            int actcol = nt * 64 + (wn * 2 + qi) * 16 + l15;
            float be = b1[e * TWO_I + 2 * actcol];
            float bo = b1[e * TWO_I + 2 * actcol + 1];
            f32x4 De = acc[mi][qi * 2], Do = acc[mi][qi * 2 + 1];
#pragma unroll
            for (int rg = 0; rg < 4; rg++) {
                if (!rval[rg]) continue;
                float he = De[rg] + be, ho = Do[rg] + bo;
                float glu = fminf(he, LIMIT);
                float lin = fminf(fmaxf(ho, -LIMIT), LIMIT);
                float a = glu * (1.f / (1.f + __expf(-ALPHA * glu))) * (lin + 1.f);
                act[(size_t)rinfo[rg] * I_DIM + actcol] = f2b(a);
            }
        }
    }
}

// ---------------------------------------------------------------------------
// Kernel 3: GEMM2 (y = act @ W2^T + b2) * softmax_weight -> atomicAdd into out
// (out pre-initialized to x by prep_kernel). W2 read as fp32, same staging.
// 64x128 tile. grid: x=nt(8), y=mt(32 early-exit), z=e.
// ---------------------------------------------------------------------------
__global__ __launch_bounds__(256, 1) void ffn2_kernel(
    const u16* __restrict__ act, const float* __restrict__ w2,
    const float* __restrict__ b2, const int* __restrict__ cnt,
    const int* __restrict__ pairs, const float* __restrict__ pweight,
    float* __restrict__ out)
{
    const int e = blockIdx.z, nt = blockIdx.x, mt = blockIdx.y;
    const int cnt_e = cnt[e * CNT_STRIDE];
    if (mt * 64 >= cnt_e) return;
    const int tid = threadIdx.x;

    __shared__ u16 As[64 * 64];
    __shared__ u16 Bs[128 * 64];

    const float* w2e = w2 + (size_t)e * H_DIM * I_DIM;
    const int* plist = pairs + e * 2048;

    const u16* aptr[2]; int ldsA[2];
#pragma unroll
    for (int i = 0; i < 2; i++) {
        int c = tid + i * 256;
        int r = c >> 3, kc = c & 7;
        int kcs = kc ^ (r & 7);
        int gr = mt * 64 + r;
        int info = (gr < cnt_e) ? plist[gr] : plist[0];
        aptr[i] = act + (size_t)info * I_DIM + kcs * 8;
        ldsA[i] = c * 8;
    }
    const float* bptr[4]; int ldsB[4];
#pragma unroll
    for (int i = 0; i < 4; i++) {
        int c = tid + i * 256;
        int r = c >> 3, kc = c & 7;
        int kcs = kc ^ (r & 7);
        bptr[i] = w2e + (size_t)(nt * 128 + r) * I_DIM + kc * 8;
        ldsB[i] = r * 64 + kcs * 8;
    }

    const int lane = tid & 63, wid = tid >> 6;
    const int wm = wid >> 1, wn = wid & 1;
    const int l15 = lane & 15, quad = lane >> 4;
    const int swz = l15 & 7;

    f32x4 acc[2][4];
#pragma unroll
    for (int mi = 0; mi < 2; mi++)
#pragma unroll
        for (int ni = 0; ni < 4; ni++) acc[mi][ni] = (f32x4){0.f, 0.f, 0.f, 0.f};

    BFragF fb[4];
#pragma unroll
    for (int i = 0; i < 4; i++) fb[i].load(bptr[i]);

    for (int ki = 0; ki < 16; ki++) {
        __syncthreads();
#pragma unroll
        for (int i = 0; i < 2; i++) gl_lds16(aptr[i] + ki * 64, &As[ldsA[i]]);
#pragma unroll
        for (int i = 0; i < 4; i++) *(short8*)(&Bs[ldsB[i]]) = fb[i].get();
        __syncthreads();
        if (ki < 15) {
#pragma unroll
            for (int i = 0; i < 4; i++) fb[i].load(bptr[i] + (ki + 1) * 64);
        }
#pragma unroll
        for (int ks = 0; ks < 2; ks++) {
            short8 af[2], bfr[4];
#pragma unroll
            for (int mi = 0; mi < 2; mi++)
                af[mi] = *(const short8*)(&As[(wm * 32 + mi * 16 + l15) * 64 + (((ks << 2) + quad) ^ swz) * 8]);
#pragma unroll
            for (int ni = 0; ni < 4; ni++)
                bfr[ni] = *(const short8*)(&Bs[(wn * 64 + ni * 16 + l15) * 64 + (((ks << 2) + quad) ^ swz) * 8]);
#pragma unroll
            for (int mi = 0; mi < 2; mi++)
#pragma unroll
                for (int ni = 0; ni < 4; ni++)
                    acc[mi][ni] = __builtin_amdgcn_mfma_f32_16x16x32_bf16(af[mi], bfr[ni], acc[mi][ni], 0, 0, 0);
        }
    }

#pragma unroll
    for (int mi = 0; mi < 2; mi++) {
        int rloc = wm * 32 + mi * 16 + quad * 4;
        int rinfo[4]; bool rval[4]; float wp[4];
#pragma unroll
        for (int rg = 0; rg < 4; rg++) {
            int gr = mt * 64 + rloc + rg;
            rval[rg] = gr < cnt_e;
            rinfo[rg] = rval[rg] ? plist[gr] : 0;
            wp[rg] = rval[rg] ? pweight[rinfo[rg]] : 0.f;
        }
#pragma unroll
        for (int ni = 0; ni < 4; ni++) {
            int hc = nt * 128 + wn * 64 + ni * 16 + l15;
            float bv = b2[e * H_DIM + hc];
#pragma unroll
            for (int rg = 0; rg < 4; rg++) {
                if (!rval[rg]) continue;
                float val = (acc[mi][ni][rg] + bv) * wp[rg];
                atomicAdd(&out[(size_t)(rinfo[rg] >> 2) * H_DIM + hc], val);
            }
        }
    }
}

extern "C" void kernel_launch(void* const* d_in, const int* in_sizes, int n_in,
                              void* d_out, int out_size, void* d_ws, size_t ws_size,
                              hipStream_t stream)
{
    const float* x      = (const float*)d_in[0];
    const float* nscale = (const float*)d_in[1];
    const float* gate_w = (const float*)d_in[2];
    const float* gate_b = (const float*)d_in[3];
    const float* mlp1_w = (const float*)d_in[4];
    const float* mlp1_b = (const float*)d_in[5];
    const float* mlp2_w = (const float*)d_in[6];
    const float* mlp2_b = (const float*)d_in[7];
    float* out = (float*)d_out;

    char* ws = (char*)d_ws;
    u16*   t_ws  = (u16*)(ws);                          //  0M: 4 MiB bf16 tokens
    u16*   act   = (u16*)(ws + (4ull << 20));           //  4M: 16 MiB bf16 act
    int*   cnt   = (int*)(ws + (20ull << 20));          // 20M: padded counters (16 x 256B)
    int*   pairs = (int*)(ws + (20ull << 20) + 4096);
    float* pw    = (float*)(ws + (20ull << 20) + 4096 + E_NUM * 2048 * 4);

    hipMemsetAsync(cnt, 0, E_NUM * CNT_STRIDE * sizeof(int), stream);

    prep_kernel<<<T_TOK, 256, 0, stream>>>(x, nscale, gate_w, gate_b, t_ws, cnt, pairs, pw, out);
    ffn1_kernel<<<dim3(16, 32, E_NUM), 256, 0, stream>>>(t_ws, mlp1_w, mlp1_b, cnt, pairs, act);
    ffn2_kernel<<<dim3(8, 32, E_NUM), 256, 0, stream>>>(act, mlp2_w, mlp2_b, cnt, pairs, pw, out);
}